// Round 13
// baseline (317.614 us; speedup 1.0000x reference)
//
#include <hip/hip_runtime.h>

#define NN 500000
#define FF 128
#define HH 128
#define BB 32768
#define KHOPS 4
#define EPER 524288              // RWS * B = 2^19
#define KE (KHOPS * EPER)        // 2097152
#define NOUT 8
#define SBLK 256                 // sort blocks
#define EPB (KE / SBLK)          // 8192 edges per sort block
#define GEMM_TILES 7813          // ceil(NN/64)

typedef unsigned short u16;
typedef unsigned char u8;
typedef __attribute__((ext_vector_type(8))) short short8v;   // 8 bf16 (4 VGPRs)
typedef __attribute__((ext_vector_type(4))) float f32x4;

__device__ __forceinline__ float bflo(unsigned int u) {
    union { unsigned int x; float f; } t; t.x = u << 16; return t.f;
}
__device__ __forceinline__ float bfhi(unsigned int u) {
    union { unsigned int x; float f; } t; t.x = u & 0xFFFF0000u; return t.f;
}
__device__ __forceinline__ u16 f2bf(float f) {
    union { float f; unsigned int u; } t; t.f = f;
    unsigned int u = t.u;
    unsigned int r = (u + 0x7FFFu + ((u >> 16) & 1u)) >> 16;   // RNE
    return (u16)r;
}
// async global->LDS, 16B per lane; LDS dest = wave-uniform base + lane*16
__device__ __forceinline__ void gload_lds16(const void* g, void* l) {
    __builtin_amdgcn_global_load_lds(
        (const __attribute__((address_space(1))) void*)g,
        (__attribute__((address_space(3))) void*)l, 16, 0, 0);
}

// ---------- deg-sum (two-stage, deterministic) ----------
__global__ void k_degsum1(const float* __restrict__ deg, const int* __restrict__ batch,
                          float* __restrict__ partial) {
    __shared__ float red[256];
    int i = blockIdx.x * 256 + threadIdx.x;       // exactly B = 128*256
    red[threadIdx.x] = deg[batch[i]];
    __syncthreads();
    for (int off = 128; off > 0; off >>= 1) {
        if (threadIdx.x < off) red[threadIdx.x] += red[threadIdx.x + off];
        __syncthreads();
    }
    if (threadIdx.x == 0) partial[blockIdx.x] = red[0];
}
__global__ void k_degsum2(const float* __restrict__ partial, float* __restrict__ dsum) {
    __shared__ float red[128];
    red[threadIdx.x] = partial[threadIdx.x];
    __syncthreads();
    for (int off = 64; off > 0; off >>= 1) {
        if (threadIdx.x < off) red[threadIdx.x] += red[threadIdx.x + off];
        __syncthreads();
    }
    if (threadIdx.x == 0) *dsum = red[0];
}

// ---------- precompute dis[e]=rsqrt(deg[e]), disb[b]=rsqrt(deg[batch[b]])*scale ----
__global__ void k_prep(const float* __restrict__ deg, const int* __restrict__ batch,
                       const float* __restrict__ dsum,
                       float* __restrict__ dis, float* __restrict__ disb) {
    int i = blockIdx.x * 256 + threadIdx.x;
    if (i < NN) dis[i] = rsqrtf(deg[i]);
    if (i < BB) disb[i] = rsqrtf(deg[batch[i]]) * (dsum[0] * (1.0f / (float)EPER));
}

// ---------- counting-sort CSR build (LDS atomics only, u8 counts) ----------
__launch_bounds__(256, 2)
__global__ void k_hist2(const int* __restrict__ heads, u8* __restrict__ M) {
    __shared__ unsigned int hp[8192];    // 32768 u8 counts, 32 KB
    int tid = threadIdx.x, blk = blockIdx.x;
    #pragma unroll
    for (int j = 0; j < 32; j++) hp[tid + j * 256] = 0;
    __syncthreads();
    int ebase = blk * EPB;
    #pragma unroll 4
    for (int it = 0; it < EPB / 256; it++) {
        int b = heads[ebase + it * 256 + tid];
        atomicAdd(&hp[b >> 2], 1u << ((b & 3) * 8));
    }
    __syncthreads();
    unsigned int* M32 = (unsigned int*)(M + (size_t)blk * BB);
    #pragma unroll
    for (int j = 0; j < 32; j++) {
        int w = tid + j * 256;
        M32[w] = hp[w];
    }
}

__global__ void k_colscan(u8* __restrict__ M, int* __restrict__ colsum) {
    int key = blockIdx.x * 256 + threadIdx.x;   // 128 blocks x 256
    unsigned int run = 0;
    #pragma unroll 8
    for (int b = 0; b < SBLK; b++) {
        size_t idx = (size_t)b * BB + key;
        u8 v = M[idx];
        M[idx] = (u8)run;               // per-key totals ~64 << 255
        run += v;
    }
    colsum[key] = (int)run;
}

__global__ void k_scan(const int* __restrict__ colsum, int* __restrict__ base) {
    __shared__ int sc[1024];
    int tid = threadIdx.x;
    int loc[32];
    int run = 0;
    #pragma unroll
    for (int j = 0; j < 32; j++) {
        loc[j] = run;
        run += colsum[tid * 32 + j];
    }
    sc[tid] = run;
    __syncthreads();
    for (int off = 1; off < 1024; off <<= 1) {
        int v = (tid >= off) ? sc[tid - off] : 0;
        __syncthreads();
        sc[tid] += v;
        __syncthreads();
    }
    int excl = sc[tid] - run;
    #pragma unroll
    for (int j = 0; j < 32; j++) base[tid * 32 + j] = excl + loc[j];
    if (tid == 1023) base[BB] = sc[1023];     // = KE
}

// ---------- pack W0 (fp32 [128][128]) into MFMA B-fragment order, bf16 ----------
__global__ void k_packW0(const float* __restrict__ W0, u16* __restrict__ w0p) {
    int f = blockIdx.x * 256 + threadIdx.x;   // 16384 total
    int k = f >> 7, c = f & 127;
    int kt = k >> 5, i = k & 7, lh = (k >> 3) & 3;
    int lane = lh * 16 + (c & 15), n = c >> 4;
    w0p[(((kt * 8 + n) * 64 + lane) << 3) + i] = f2bf(W0[f]);
}

// ---------- fused: scatter2 (blocks 0..255) + GEMM1 (blocks 256..) ----------
// GEMM path: 64-row tile; x staged RAW fp32 via async global_load_lds with
// pre-swizzled global source (LDS linear dest, XOR on source address -> the
// fragment read-back is bank-conflict-free). No VGPR round-trip for staging:
// whole 32 KB tile in flight per block.
__launch_bounds__(256, 2)
__global__ void k_fused(const float* __restrict__ x, const u16* __restrict__ w0p,
                        const float* __restrict__ b0, u16* __restrict__ h,
                        const int* __restrict__ heads, const int* __restrict__ ends,
                        const u8* __restrict__ M, const int* __restrict__ base,
                        unsigned int* __restrict__ pe) {
    __shared__ float xs[8192];        // 32 KB fp32 x-tile (swizzled content)
    __shared__ u16 ws[16384];         // 32 KB packed B | scatter hist
    int tid = threadIdx.x;

    if (blockIdx.x < SBLK) {
        // ---- scatter packed (hop<<19)|end into pos = base[b]+M[blk][b]+rank ----
        unsigned int* hp = (unsigned int*)ws;
        int blk = blockIdx.x;
        #pragma unroll
        for (int j = 0; j < 32; j++) hp[tid + j * 256] = 0;
        __syncthreads();
        int ebase = blk * EPB;
        for (int it = 0; it < EPB / 256; it++) {
            int i = ebase + it * 256 + tid;
            int b = heads[i];
            unsigned int e = (unsigned int)ends[i];
            unsigned int kk = (unsigned int)(i >> 19);   // EPER = 2^19
            unsigned int old = atomicAdd(&hp[b >> 2], 1u << ((b & 3) * 8));
            unsigned int rank = (old >> ((b & 3) * 8)) & 0xFFu;
            int pos = base[b] + (int)M[(size_t)blk * BB + b] + (int)rank;
            pe[pos] = (kk << 19) | e;
        }
        return;
    }

    // ---- GEMM1: h = bf16(relu(x @ W0 + b0)) for one 64-row tile ----
    int wid = tid >> 6;
    int lane = tid & 63;
    long rowbase = (long)(blockIdx.x - SBLK) * 64;

    // stage packed B: 2048 chunks of 16B, linear (8 waves-iters)
    #pragma unroll
    for (int it = 0; it < 8; it++) {
        int cbase = it * 256 + wid * 64;              // wave-uniform chunk base
        gload_lds16((const char*)w0p + (size_t)(cbase + lane) * 16,
                    (char*)ws + (size_t)cbase * 16);
    }
    // stage x tile: 64 rows x 32 chunks(16B). LDS position p = c ^ (row&7);
    // source address carries the swizzle: chunk stored at p is c = p ^ (row&7).
    #pragma unroll
    for (int it = 0; it < 8; it++) {
        int cbase = it * 256 + wid * 64;              // wave-uniform
        int ci = cbase + lane;
        int row = ci >> 5;
        int p = ci & 31;
        int c = p ^ (row & 7);
        long grow = rowbase + row; if (grow >= NN) grow = NN - 1;
        gload_lds16((const char*)x + (grow << 9) + (c << 4),
                    (char*)xs + (size_t)cbase * 16);
    }
    __syncthreads();                  // drains vmcnt (async LDS writes done)

    // A fragments from LDS fp32 (swizzled addr), convert to bf16 in regs.
    // Wave owns 16 rows: r = wid*16 + (lane&15).
    short8v a[4];
    {
        int r = wid * 16 + (lane & 15);
        int sw = r & 7;
        #pragma unroll
        for (int kt = 0; kt < 4; kt++) {
            int c0 = kt * 8 + (lane >> 4) * 2;
            float4 v0 = *(const float4*)((const char*)xs + r * 512 + ((c0 ^ sw) << 4));
            float4 v1 = *(const float4*)((const char*)xs + r * 512 + (((c0 + 1) ^ sw) << 4));
            short8v f;
            f[0] = (short)f2bf(v0.x); f[1] = (short)f2bf(v0.y);
            f[2] = (short)f2bf(v0.z); f[3] = (short)f2bf(v0.w);
            f[4] = (short)f2bf(v1.x); f[5] = (short)f2bf(v1.y);
            f[6] = (short)f2bf(v1.z); f[7] = (short)f2bf(v1.w);
            a[kt] = f;
        }
    }

    f32x4 acc[8] = {};
    #pragma unroll
    for (int n = 0; n < 8; n++) {
        short8v bfr[4];
        #pragma unroll
        for (int kt = 0; kt < 4; kt++)
            bfr[kt] = *(const short8v*)&ws[(((kt * 8 + n) * 64 + lane) << 3)];
        #pragma unroll
        for (int kt = 0; kt < 4; kt++)
            acc[n] = __builtin_amdgcn_mfma_f32_16x16x32_bf16(a[kt], bfr[kt],
                                                             acc[n], 0, 0, 0);
    }

    float b0v[8];
    #pragma unroll
    for (int n = 0; n < 8; n++) b0v[n] = b0[n * 16 + (lane & 15)];

    // epilogue: stage relu(acc)+b0 in wave-private 4 KB stripe of xs, then
    // coalesced dwordx4 stores
    __syncthreads();                  // all A/B LDS reads done before overwrite
    u16* xw = (u16*)xs + wid * 16 * 128;
    #pragma unroll
    for (int r = 0; r < 4; r++) {
        int row = (lane >> 4) * 4 + r;        // 0..15 in stripe
        int sw = (row & 7) << 4;
        #pragma unroll
        for (int n = 0; n < 8; n++) {
            float v = acc[n][r] + b0v[n];
            v = v > 0.f ? v : 0.f;
            int byte = row * 256 + ((n * 32 + (lane & 15) * 2) ^ sw);
            *(u16*)((char*)xw + byte) = f2bf(v);
        }
    }
    __syncthreads();
    #pragma unroll
    for (int pass = 0; pass < 4; pass++) {
        int off = pass * 1024 + lane * 16;   // byte offset in 4 KB stripe
        int row = off >> 8;                  // 0..15
        int colb = off & 255;
        int ocolb = colb ^ ((row & 7) << 4);
        long grow = rowbase + wid * 16 + row;
        uint4 v = *(const uint4*)((const char*)xw + off);
        if (grow < NN)
            *(uint4*)((char*)&h[grow * 128] + ocolb) = v;
    }
}

// ---------- gather: P[b,:] = att0*h[batch[b],:] + sum_j w_j * h[end_j,:] ----------
// 4 waves/block, wave owns row b. Quarter-wave q owns edge j+u*4+q; lane owns
// 8 cols. Unroll 8: 32 independent h-row loads in flight per wave.
__launch_bounds__(256)
__global__ void k_gather(const u16* __restrict__ h, const int* __restrict__ batch,
                         const int* __restrict__ base, const unsigned int* __restrict__ pe,
                         const float* __restrict__ dis, const float* __restrict__ disb,
                         const float* __restrict__ att,
                         float* __restrict__ P, float* __restrict__ s) {
    int b = blockIdx.x * 4 + (threadIdx.x >> 6);
    int l = threadIdx.x & 63;
    int q = l >> 4;
    int c8 = (l & 15) * 8;            // owns cols c8..c8+7
    float att0 = att[0];
    float a1 = att[1], a2 = att[2], a3 = att[3], a4 = att[4];
    float dbv = disb[b];
    float acc[8] = {0.f, 0.f, 0.f, 0.f, 0.f, 0.f, 0.f, 0.f};

    if (q == 0) {
        int nb = batch[b];
        uint4 v = *(const uint4*)&h[(size_t)nb * 128 + c8];
        acc[0] = att0 * bflo(v.x); acc[1] = att0 * bfhi(v.x);
        acc[2] = att0 * bflo(v.y); acc[3] = att0 * bfhi(v.y);
        acc[4] = att0 * bflo(v.z); acc[5] = att0 * bfhi(v.z);
        acc[6] = att0 * bflo(v.w); acc[7] = att0 * bfhi(v.w);
    }

    int beg = base[b], fin = base[b + 1];
    float wsum = 0.f;
    for (int j = beg; j < fin; j += 32) {
        unsigned int p[8];
        #pragma unroll
        for (int u = 0; u < 8; u++) {
            int je = j + u * 4 + q;
            int jc = je < fin ? je : beg;     // always-valid index
            p[u] = pe[jc];
            if (je >= fin) p[u] |= 0x80000000u;   // mark dead
        }
        float wv[8];
        uint4 v[8];
        #pragma unroll
        for (int u = 0; u < 8; u++) {
            int e = (int)(p[u] & 0x7FFFFu);
            int kk = (int)((p[u] >> 19) & 3u);
            float av = (kk < 2) ? (kk == 0 ? a1 : a2) : (kk == 2 ? a3 : a4);
            float w = av * dbv * dis[e];
            wv[u] = (p[u] & 0x80000000u) ? 0.f : w;
            v[u] = *(const uint4*)&h[(size_t)e * 128 + c8];
        }
        #pragma unroll
        for (int u = 0; u < 8; u++) {
            float w = wv[u];
            acc[0] += w * bflo(v[u].x); acc[1] += w * bfhi(v[u].x);
            acc[2] += w * bflo(v[u].y); acc[3] += w * bfhi(v[u].y);
            acc[4] += w * bflo(v[u].z); acc[5] += w * bfhi(v[u].z);
            acc[6] += w * bflo(v[u].w); acc[7] += w * bfhi(v[u].w);
            wsum += w;
        }
    }
    #pragma unroll
    for (int k = 0; k < 8; k++) {
        acc[k] += __shfl_xor(acc[k], 16);
        acc[k] += __shfl_xor(acc[k], 32);
    }
    wsum += __shfl_xor(wsum, 16);
    wsum += __shfl_xor(wsum, 32);

    if (q == 0) {
        float4 o0 = { acc[0], acc[1], acc[2], acc[3] };
        float4 o1 = { acc[4], acc[5], acc[6], acc[7] };
        *(float4*)&P[(size_t)b * 128 + c8]     = o0;
        *(float4*)&P[(size_t)b * 128 + c8 + 4] = o1;
        if (l == 0) s[b] = att0 + wsum;
    }
}

// ---------- fused epilogue: aggx = P@W1 + s*b1; relu; @W2 + b2; log_softmax ----------
__launch_bounds__(256, 2)
__global__ void k_out(const float* __restrict__ P, const float* __restrict__ s,
                      const float* __restrict__ W1, const float* __restrict__ b1,
                      const float* __restrict__ W2, const float* __restrict__ b2,
                      float* __restrict__ out) {
    __shared__ float W1s[128 * 128];  // 64 KB
    __shared__ float Ps[32 * 128];    // 16 KB, reused as relu(aggx)
    int tid = threadIdx.x;
    int rowbase = blockIdx.x * 32;
    #pragma unroll
    for (int rep = 0; rep < 16; rep++) {
        int f = tid + rep * 256;
        *(float4*)&W1s[f * 4] = *(const float4*)&W1[f * 4];
    }
    #pragma unroll
    for (int rep = 0; rep < 4; rep++) {
        int f = tid + rep * 256;
        *(float4*)&Ps[f * 4] = *(const float4*)&P[(size_t)rowbase * 128 + f * 4];
    }
    __syncthreads();

    int c0 = (tid & 31) * 4;
    int r0 = (tid >> 5) * 4;
    float b1r[4] = { b1[c0], b1[c0 + 1], b1[c0 + 2], b1[c0 + 3] };
    float sv[4];
    #pragma unroll
    for (int j = 0; j < 4; j++) sv[j] = s[rowbase + r0 + j];

    float acc[4][4] = {};
    #pragma unroll 2
    for (int i = 0; i < 128; i += 4) {
        float4 xq[4], wq4[4];
        #pragma unroll
        for (int j = 0; j < 4; j++) xq[j]  = *(const float4*)&Ps[(r0 + j) * 128 + i];
        #pragma unroll
        for (int q = 0; q < 4; q++) wq4[q] = *(const float4*)&W1s[(i + q) * 128 + c0];
        #pragma unroll
        for (int j = 0; j < 4; j++) {
            float xv[4] = { xq[j].x, xq[j].y, xq[j].z, xq[j].w };
            #pragma unroll
            for (int q = 0; q < 4; q++) {
                acc[j][0] += xv[q] * wq4[q].x;
                acc[j][1] += xv[q] * wq4[q].y;
                acc[j][2] += xv[q] * wq4[q].z;
                acc[j][3] += xv[q] * wq4[q].w;
            }
        }
    }
    __syncthreads();                  // all reads of Ps done before overwrite
    #pragma unroll
    for (int j = 0; j < 4; j++) {
        #pragma unroll
        for (int c = 0; c < 4; c++) {
            float v = acc[j][c] + sv[j] * b1r[c];
            Ps[(r0 + j) * 128 + c0 + c] = v > 0.f ? v : 0.f;
        }
    }
    __syncthreads();

    int row = tid >> 3;
    int o = tid & 7;
    int rot = (row * 4) & 127;
    float v = b2[o];
    #pragma unroll 4
    for (int ii = 0; ii < 128; ii++) {
        int i = (ii + rot) & 127;
        v += Ps[row * 128 + i] * W2[i * 8 + o];
    }
    float m = v;
    for (int d = 1; d < 8; d <<= 1) m = fmaxf(m, __shfl_xor(m, d, 8));
    float ex = expf(v - m);
    float sum = ex;
    for (int d = 1; d < 8; d <<= 1) sum += __shfl_xor(sum, d, 8);
    out[(size_t)(rowbase + row) * 8 + o] = (v - m) - logf(sum);
}

extern "C" void kernel_launch(void* const* d_in, const int* in_sizes, int n_in,
                              void* d_out, int out_size, void* d_ws, size_t ws_size,
                              hipStream_t stream) {
    const float* x     = (const float*)d_in[0];
    const float* W0    = (const float*)d_in[1];
    const float* b0    = (const float*)d_in[2];
    const float* W1    = (const float*)d_in[3];
    const float* b1    = (const float*)d_in[4];
    const float* W2    = (const float*)d_in[5];
    const float* b2    = (const float*)d_in[6];
    const float* att   = (const float*)d_in[7];
    const float* deg   = (const float*)d_in[8];
    const int*   batch = (const int*)d_in[9];
    const int*   heads = (const int*)d_in[10];
    const int*   ends  = (const int*)d_in[11];
    float* out = (float*)d_out;

    char* w = (char*)d_ws;
    size_t off = 0;
    u16* h = (u16*)(w + off);          off += (size_t)NN * 128 * 2;       // 128 MB
    float* P = (float*)(w + off);      off += (size_t)BB * 128 * 4;       // 16 MB
    float* s = (float*)(w + off);      off += (size_t)BB * 4;
    int* base = (int*)(w + off);       off += 131328;                     // (B+1)*4 padded
    unsigned int* pe = (unsigned int*)(w + off); off += (size_t)KE * 4;   // packed (k,e)
    u8* M = (u8*)(w + off);            off += (size_t)SBLK * BB;          // 8 MB hist
    int* colsum = (int*)(w + off);     off += (size_t)BB * 4;
    float* dis = (float*)(w + off);    off += (size_t)NN * 4;             // rsqrt(deg)
    float* disb = (float*)(w + off);   off += (size_t)BB * 4;
    float* partial = (float*)(w + off); off += 1024;
    float* dsum = (float*)(w + off);   off += 256;
    u16* w0p = (u16*)(w + off);        off += 16384 * 2;                  // packed W0

    k_degsum1<<<128, 256, 0, stream>>>(deg, batch, partial);
    k_degsum2<<<1, 128, 0, stream>>>(partial, dsum);
    k_prep<<<(NN + 255) / 256, 256, 0, stream>>>(deg, batch, dsum, dis, disb);
    k_hist2<<<SBLK, 256, 0, stream>>>(heads, M);
    k_colscan<<<BB / 256, 256, 0, stream>>>(M, colsum);
    k_scan<<<1, 1024, 0, stream>>>(colsum, base);
    k_packW0<<<64, 256, 0, stream>>>(W0, w0p);
    k_fused<<<SBLK + GEMM_TILES, 256, 0, stream>>>(x, w0p, b0, h, heads, ends,
                                                   M, base, pe);
    k_gather<<<BB / 4, 256, 0, stream>>>(h, batch, base, pe, dis, disb, att, P, s);
    k_out<<<BB / 32, 256, 0, stream>>>(P, s, W1, b1, W2, b2, out);
}

// Round 14
// 298.496 us; speedup vs baseline: 1.0640x; 1.0640x over previous
//
#include <hip/hip_runtime.h>

#define NN 500000
#define FF 128
#define HH 128
#define BB 32768
#define KHOPS 4
#define EPER 524288              // RWS * B = 2^19
#define KE (KHOPS * EPER)        // 2097152
#define NOUT 8
#define SBLK 256                 // sort blocks
#define EPB (KE / SBLK)          // 8192 edges per sort block

typedef unsigned short u16;
typedef unsigned char u8;
typedef __attribute__((ext_vector_type(8))) short short8v;   // 8 bf16 (4 VGPRs)
typedef __attribute__((ext_vector_type(4))) float f32x4;

__device__ __forceinline__ float bflo(unsigned int u) {
    union { unsigned int x; float f; } t; t.x = u << 16; return t.f;
}
__device__ __forceinline__ float bfhi(unsigned int u) {
    union { unsigned int x; float f; } t; t.x = u & 0xFFFF0000u; return t.f;
}
__device__ __forceinline__ u16 f2bf(float f) {
    union { float f; unsigned int u; } t; t.f = f;
    unsigned int u = t.u;
    unsigned int r = (u + 0x7FFFu + ((u >> 16) & 1u)) >> 16;   // RNE
    return (u16)r;
}

// ---------- layer A: hist2 (0..255) | degsum partials (256..383) | dis (384..) ----
__launch_bounds__(256, 2)
__global__ void k_preA(const int* __restrict__ heads, u8* __restrict__ M,
                       const float* __restrict__ deg, const int* __restrict__ batch,
                       float* __restrict__ partial, float* __restrict__ dis) {
    __shared__ unsigned int hp[8192];    // 32 KB hist / 1 KB reduce
    int tid = threadIdx.x;
    int bid = blockIdx.x;
    if (bid < SBLK) {
        // per-block histogram of heads into M[bid][BB] (u8, 4-packed)
        #pragma unroll
        for (int j = 0; j < 32; j++) hp[tid + j * 256] = 0;
        __syncthreads();
        int ebase = bid * EPB;
        #pragma unroll 4
        for (int it = 0; it < EPB / 256; it++) {
            int b = heads[ebase + it * 256 + tid];
            atomicAdd(&hp[b >> 2], 1u << ((b & 3) * 8));
        }
        __syncthreads();
        unsigned int* M32 = (unsigned int*)(M + (size_t)bid * BB);
        #pragma unroll
        for (int j = 0; j < 32; j++) {
            int w = tid + j * 256;
            M32[w] = hp[w];
        }
    } else if (bid < SBLK + 128) {
        // deg-sum partial over 256 batch entries
        float* red = (float*)hp;
        int i = (bid - SBLK) * 256 + tid;
        red[tid] = deg[batch[i]];
        __syncthreads();
        for (int off = 128; off > 0; off >>= 1) {
            if (tid < off) red[tid] += red[tid + off];
            __syncthreads();
        }
        if (tid == 0) partial[bid - SBLK] = red[0];
    } else {
        // dis[i] = rsqrt(deg[i]), 1024 elements per block
        int i0 = (bid - SBLK - 128) * 1024 + tid * 4;
        if (i0 < NN) {                       // NN % 4 == 0
            float4 d = *(const float4*)&deg[i0];
            float4 o;
            o.x = rsqrtf(d.x); o.y = rsqrtf(d.y);
            o.z = rsqrtf(d.z); o.w = rsqrtf(d.w);
            *(float4*)&dis[i0] = o;
        }
    }
}

// ---------- layer B: degsum2 (block 0) | colscan u32 (blocks 1..32) ----------
__global__ void k_preB(const float* __restrict__ partial, float* __restrict__ dsum,
                       u8* __restrict__ M, int* __restrict__ colsum) {
    int tid = threadIdx.x;
    if (blockIdx.x == 0) {
        __shared__ float red[128];
        if (tid < 128) red[tid] = partial[tid];
        __syncthreads();
        for (int off = 64; off > 0; off >>= 1) {
            if (tid < off) red[tid] += red[tid + off];
            __syncthreads();
        }
        if (tid == 0) dsum[0] = red[0];
    } else {
        // exclusive prefix down each key column, 4 keys/thread byte-parallel
        int g = (blockIdx.x - 1) * 256 + tid;    // key-group (8192 total)
        unsigned int* M32 = (unsigned int*)M;
        unsigned int run = 0;
        #pragma unroll 8
        for (int b = 0; b < SBLK; b++) {
            size_t idx = (size_t)b * (BB / 4) + g;
            unsigned int v = M32[idx];
            M32[idx] = run;
            run += v;     // per-byte totals <= ~120, no cross-byte carry
        }
        colsum[g * 4 + 0] = (int)(run & 0xFFu);
        colsum[g * 4 + 1] = (int)((run >> 8) & 0xFFu);
        colsum[g * 4 + 2] = (int)((run >> 16) & 0xFFu);
        colsum[g * 4 + 3] = (int)((run >> 24) & 0xFFu);
    }
}

// ---------- layer C: scan (block 0) | disb (1..32) | packW0 (33..48) ----------
__global__ void k_preC(const int* __restrict__ colsum, int* __restrict__ base,
                       const float* __restrict__ deg, const int* __restrict__ batch,
                       const float* __restrict__ dsum, float* __restrict__ disb,
                       const float* __restrict__ W0, u16* __restrict__ w0p) {
    int tid = threadIdx.x;                       // 1024 threads
    if (blockIdx.x == 0) {
        __shared__ int sc[1024];
        int loc[32];
        int run = 0;
        #pragma unroll
        for (int j = 0; j < 32; j++) {
            loc[j] = run;
            run += colsum[tid * 32 + j];
        }
        sc[tid] = run;
        __syncthreads();
        for (int off = 1; off < 1024; off <<= 1) {
            int v = (tid >= off) ? sc[tid - off] : 0;
            __syncthreads();
            sc[tid] += v;
            __syncthreads();
        }
        int excl = sc[tid] - run;
        #pragma unroll
        for (int j = 0; j < 32; j++) base[tid * 32 + j] = excl + loc[j];
        if (tid == 1023) base[BB] = sc[1023];    // = KE
    } else if (blockIdx.x <= 32) {
        int b = (blockIdx.x - 1) * 1024 + tid;
        float sc2 = dsum[0] * (1.0f / (float)EPER);
        disb[b] = rsqrtf(deg[batch[b]]) * sc2;
    } else {
        int f = (blockIdx.x - 33) * 1024 + tid;  // 16384 total
        int k = f >> 7, c = f & 127;
        int kt = k >> 5, i = k & 7, lh = (k >> 3) & 3;
        int lane = lh * 16 + (c & 15), n = c >> 4;
        w0p[(((kt * 8 + n) * 64 + lane) << 3) + i] = f2bf(W0[f]);
    }
}

// ---------- scatter packed (hop<<19)|end into pos = base[b]+M[blk][b]+rank ----------
__launch_bounds__(256, 2)
__global__ void k_scatter2(const int* __restrict__ heads, const int* __restrict__ ends,
                           const u8* __restrict__ M, const int* __restrict__ base,
                           unsigned int* __restrict__ pe) {
    __shared__ unsigned int hp[8192];
    int tid = threadIdx.x, blk = blockIdx.x;
    #pragma unroll
    for (int j = 0; j < 32; j++) hp[tid + j * 256] = 0;
    __syncthreads();
    int ebase = blk * EPB;
    for (int it = 0; it < EPB / 256; it++) {
        int i = ebase + it * 256 + tid;
        int b = heads[i];
        unsigned int e = (unsigned int)ends[i];
        unsigned int kk = (unsigned int)(i >> 19);   // EPER = 2^19
        unsigned int old = atomicAdd(&hp[b >> 2], 1u << ((b & 3) * 8));
        unsigned int rank = (old >> ((b & 3) * 8)) & 0xFFu;
        int pos = base[b] + (int)M[(size_t)blk * BB + b] + (int)rank;
        pe[pos] = (kk << 19) | e;
    }
}

// ---------- GEMM1 (MFMA): h = bf16(relu(x @ W0 + b0)) over all N nodes ----------
// A-fragments loaded DIRECTLY from global x; LDS = 32 KB ws only.
__launch_bounds__(256, 2)
__global__ void k_gemm1(const float* __restrict__ x, const u16* __restrict__ w0p,
                        const float* __restrict__ b0, u16* __restrict__ h) {
    __shared__ u16 ws[16384];         // 32 KB: packed B; later store-staging
    int tid = threadIdx.x;
    int wid = tid >> 6;
    int lane = tid & 63;
    long rowbase = (long)blockIdx.x * 128;

    #pragma unroll
    for (int r = 0; r < 8; r++) {
        int f = tid + r * 256;        // 2048 x 16B
        *(float4*)&ws[f * 8] = *(const float4*)&w0p[f * 8];
    }

    short8v a[2][4];
    int qc = (lane >> 4) * 8;
    #pragma unroll
    for (int rs = 0; rs < 2; rs++) {
        long grow = rowbase + wid * 32 + rs * 16 + (lane & 15);
        if (grow >= NN) grow = NN - 1;            // clamp tail
        const float* xr = &x[grow * 128 + qc];
        #pragma unroll
        for (int kt = 0; kt < 4; kt++) {
            float4 v0 = *(const float4*)&xr[kt * 32];
            float4 v1 = *(const float4*)&xr[kt * 32 + 4];
            short8v f;
            f[0] = (short)f2bf(v0.x); f[1] = (short)f2bf(v0.y);
            f[2] = (short)f2bf(v0.z); f[3] = (short)f2bf(v0.w);
            f[4] = (short)f2bf(v1.x); f[5] = (short)f2bf(v1.y);
            f[6] = (short)f2bf(v1.z); f[7] = (short)f2bf(v1.w);
            a[rs][kt] = f;
        }
    }
    __syncthreads();                  // ws ready

    f32x4 acc[2][8] = {};
    #pragma unroll
    for (int n = 0; n < 8; n++) {
        short8v bfr[4];
        #pragma unroll
        for (int kt = 0; kt < 4; kt++)
            bfr[kt] = *(const short8v*)&ws[(((kt * 8 + n) * 64 + lane) << 3)];
        #pragma unroll
        for (int rs = 0; rs < 2; rs++) {
            #pragma unroll
            for (int kt = 0; kt < 4; kt++)
                acc[rs][n] = __builtin_amdgcn_mfma_f32_16x16x32_bf16(
                                 a[rs][kt], bfr[kt], acc[rs][n], 0, 0, 0);
        }
    }

    float b0v[8];
    #pragma unroll
    for (int n = 0; n < 8; n++) b0v[n] = b0[n * 16 + (lane & 15)];

    __syncthreads();                  // all B-fragment reads done
    u16* xw = &ws[wid * 32 * 128];
    #pragma unroll
    for (int rs = 0; rs < 2; rs++) {
        #pragma unroll
        for (int r = 0; r < 4; r++) {
            int row = rs * 16 + (lane >> 4) * 4 + r;      // 0..31 in stripe
            int sw = (row & 7) << 4;
            #pragma unroll
            for (int n = 0; n < 8; n++) {
                float v = acc[rs][n][r] + b0v[n];
                v = v > 0.f ? v : 0.f;
                int byte = row * 256 + ((n * 32 + (lane & 15) * 2) ^ sw);
                *(u16*)((char*)xw + byte) = f2bf(v);
            }
        }
    }
    __syncthreads();
    #pragma unroll
    for (int pass = 0; pass < 8; pass++) {
        int off = pass * 1024 + lane * 16;   // byte offset in stripe
        int row = off >> 8;                  // 0..31
        int colb = off & 255;
        int ocolb = colb ^ ((row & 7) << 4);
        long grow = rowbase + wid * 32 + row;
        uint4 v = *(const uint4*)((const char*)xw + off);
        if (grow < NN)
            *(uint4*)((char*)&h[grow * 128] + ocolb) = v;
    }
}

// ---------- gather: P[b,:] = att0*h[batch[b],:] + sum_j w_j * h[end_j,:] ----------
// 4 waves/block, wave owns row b. Quarter-wave q owns edge j+u*4+q; lane owns
// 8 cols. Unroll 8: 32 independent h-row loads in flight per wave.
__launch_bounds__(256)
__global__ void k_gather(const u16* __restrict__ h, const int* __restrict__ batch,
                         const int* __restrict__ base, const unsigned int* __restrict__ pe,
                         const float* __restrict__ dis, const float* __restrict__ disb,
                         const float* __restrict__ att,
                         float* __restrict__ P, float* __restrict__ s) {
    int b = blockIdx.x * 4 + (threadIdx.x >> 6);
    int l = threadIdx.x & 63;
    int q = l >> 4;
    int c8 = (l & 15) * 8;            // owns cols c8..c8+7
    float att0 = att[0];
    float a1 = att[1], a2 = att[2], a3 = att[3], a4 = att[4];
    float dbv = disb[b];
    float acc[8] = {0.f, 0.f, 0.f, 0.f, 0.f, 0.f, 0.f, 0.f};

    if (q == 0) {
        int nb = batch[b];
        uint4 v = *(const uint4*)&h[(size_t)nb * 128 + c8];
        acc[0] = att0 * bflo(v.x); acc[1] = att0 * bfhi(v.x);
        acc[2] = att0 * bflo(v.y); acc[3] = att0 * bfhi(v.y);
        acc[4] = att0 * bflo(v.z); acc[5] = att0 * bfhi(v.z);
        acc[6] = att0 * bflo(v.w); acc[7] = att0 * bfhi(v.w);
    }

    int beg = base[b], fin = base[b + 1];
    float wsum = 0.f;
    for (int j = beg; j < fin; j += 32) {
        unsigned int p[8];
        #pragma unroll
        for (int u = 0; u < 8; u++) {
            int je = j + u * 4 + q;
            int jc = je < fin ? je : beg;     // always-valid index
            p[u] = pe[jc];
            if (je >= fin) p[u] |= 0x80000000u;   // mark dead
        }
        float wv[8];
        uint4 v[8];
        #pragma unroll
        for (int u = 0; u < 8; u++) {
            int e = (int)(p[u] & 0x7FFFFu);
            int kk = (int)((p[u] >> 19) & 3u);
            float av = (kk < 2) ? (kk == 0 ? a1 : a2) : (kk == 2 ? a3 : a4);
            float w = av * dbv * dis[e];
            wv[u] = (p[u] & 0x80000000u) ? 0.f : w;
            v[u] = *(const uint4*)&h[(size_t)e * 128 + c8];
        }
        #pragma unroll
        for (int u = 0; u < 8; u++) {
            float w = wv[u];
            acc[0] += w * bflo(v[u].x); acc[1] += w * bfhi(v[u].x);
            acc[2] += w * bflo(v[u].y); acc[3] += w * bfhi(v[u].y);
            acc[4] += w * bflo(v[u].z); acc[5] += w * bfhi(v[u].z);
            acc[6] += w * bflo(v[u].w); acc[7] += w * bfhi(v[u].w);
            wsum += w;
        }
    }
    #pragma unroll
    for (int k = 0; k < 8; k++) {
        acc[k] += __shfl_xor(acc[k], 16);
        acc[k] += __shfl_xor(acc[k], 32);
    }
    wsum += __shfl_xor(wsum, 16);
    wsum += __shfl_xor(wsum, 32);

    if (q == 0) {
        float4 o0 = { acc[0], acc[1], acc[2], acc[3] };
        float4 o1 = { acc[4], acc[5], acc[6], acc[7] };
        *(float4*)&P[(size_t)b * 128 + c8]     = o0;
        *(float4*)&P[(size_t)b * 128 + c8 + 4] = o1;
        if (l == 0) s[b] = att0 + wsum;
    }
}

// ---------- fused epilogue: aggx = P@W1 + s*b1; relu; @W2 + b2; log_softmax ----------
__launch_bounds__(256, 2)
__global__ void k_out(const float* __restrict__ P, const float* __restrict__ s,
                      const float* __restrict__ W1, const float* __restrict__ b1,
                      const float* __restrict__ W2, const float* __restrict__ b2,
                      float* __restrict__ out) {
    __shared__ float W1s[128 * 128];  // 64 KB
    __shared__ float Ps[32 * 128];    // 16 KB, reused as relu(aggx)
    int tid = threadIdx.x;
    int rowbase = blockIdx.x * 32;
    #pragma unroll
    for (int rep = 0; rep < 16; rep++) {
        int f = tid + rep * 256;
        *(float4*)&W1s[f * 4] = *(const float4*)&W1[f * 4];
    }
    #pragma unroll
    for (int rep = 0; rep < 4; rep++) {
        int f = tid + rep * 256;
        *(float4*)&Ps[f * 4] = *(const float4*)&P[(size_t)rowbase * 128 + f * 4];
    }
    __syncthreads();

    int c0 = (tid & 31) * 4;
    int r0 = (tid >> 5) * 4;
    float b1r[4] = { b1[c0], b1[c0 + 1], b1[c0 + 2], b1[c0 + 3] };
    float sv[4];
    #pragma unroll
    for (int j = 0; j < 4; j++) sv[j] = s[rowbase + r0 + j];

    float acc[4][4] = {};
    #pragma unroll 2
    for (int i = 0; i < 128; i += 4) {
        float4 xq[4], wq4[4];
        #pragma unroll
        for (int j = 0; j < 4; j++) xq[j]  = *(const float4*)&Ps[(r0 + j) * 128 + i];
        #pragma unroll
        for (int q = 0; q < 4; q++) wq4[q] = *(const float4*)&W1s[(i + q) * 128 + c0];
        #pragma unroll
        for (int j = 0; j < 4; j++) {
            float xv[4] = { xq[j].x, xq[j].y, xq[j].z, xq[j].w };
            #pragma unroll
            for (int q = 0; q < 4; q++) {
                acc[j][0] += xv[q] * wq4[q].x;
                acc[j][1] += xv[q] * wq4[q].y;
                acc[j][2] += xv[q] * wq4[q].z;
                acc[j][3] += xv[q] * wq4[q].w;
            }
        }
    }
    __syncthreads();                  // all reads of Ps done before overwrite
    #pragma unroll
    for (int j = 0; j < 4; j++) {
        #pragma unroll
        for (int c = 0; c < 4; c++) {
            float v = acc[j][c] + sv[j] * b1r[c];
            Ps[(r0 + j) * 128 + c0 + c] = v > 0.f ? v : 0.f;
        }
    }
    __syncthreads();

    int row = tid >> 3;
    int o = tid & 7;
    int rot = (row * 4) & 127;
    float v = b2[o];
    #pragma unroll 4
    for (int ii = 0; ii < 128; ii++) {
        int i = (ii + rot) & 127;
        v += Ps[row * 128 + i] * W2[i * 8 + o];
    }
    float m = v;
    for (int d = 1; d < 8; d <<= 1) m = fmaxf(m, __shfl_xor(m, d, 8));
    float ex = expf(v - m);
    float sum = ex;
    for (int d = 1; d < 8; d <<= 1) sum += __shfl_xor(sum, d, 8);
    out[(size_t)(rowbase + row) * 8 + o] = (v - m) - logf(sum);
}

extern "C" void kernel_launch(void* const* d_in, const int* in_sizes, int n_in,
                              void* d_out, int out_size, void* d_ws, size_t ws_size,
                              hipStream_t stream) {
    const float* x     = (const float*)d_in[0];
    const float* W0    = (const float*)d_in[1];
    const float* b0    = (const float*)d_in[2];
    const float* W1    = (const float*)d_in[3];
    const float* b1    = (const float*)d_in[4];
    const float* W2    = (const float*)d_in[5];
    const float* b2    = (const float*)d_in[6];
    const float* att   = (const float*)d_in[7];
    const float* deg   = (const float*)d_in[8];
    const int*   batch = (const int*)d_in[9];
    const int*   heads = (const int*)d_in[10];
    const int*   ends  = (const int*)d_in[11];
    float* out = (float*)d_out;

    char* w = (char*)d_ws;
    size_t off = 0;
    u16* h = (u16*)(w + off);          off += (size_t)NN * 128 * 2;       // 128 MB
    float* P = (float*)(w + off);      off += (size_t)BB * 128 * 4;       // 16 MB
    float* s = (float*)(w + off);      off += (size_t)BB * 4;
    int* base = (int*)(w + off);       off += 131328;                     // (B+1)*4 padded
    unsigned int* pe = (unsigned int*)(w + off); off += (size_t)KE * 4;   // packed (k,e)
    u8* M = (u8*)(w + off);            off += (size_t)SBLK * BB;          // 8 MB hist
    int* colsum = (int*)(w + off);     off += (size_t)BB * 4;
    float* dis = (float*)(w + off);    off += (size_t)NN * 4;             // rsqrt(deg)
    float* disb = (float*)(w + off);   off += (size_t)BB * 4;
    float* partial = (float*)(w + off); off += 1024;
    float* dsum = (float*)(w + off);   off += 256;
    u16* w0p = (u16*)(w + off);        off += 16384 * 2;                  // packed W0

    int disBlocks = (NN + 1023) / 1024;                 // 489
    k_preA<<<SBLK + 128 + disBlocks, 256, 0, stream>>>(heads, M, deg, batch,
                                                       partial, dis);
    k_preB<<<33, 256, 0, stream>>>(partial, dsum, M, colsum);
    k_preC<<<49, 1024, 0, stream>>>(colsum, base, deg, batch, dsum, disb, W0, w0p);
    k_scatter2<<<SBLK, 256, 0, stream>>>(heads, ends, M, base, pe);
    k_gemm1<<<(NN + 127) / 128, 256, 0, stream>>>(x, w0p, b0, h);
    k_gather<<<BB / 4, 256, 0, stream>>>(h, batch, base, pe, dis, disb, att, P, s);
    k_out<<<BB / 32, 256, 0, stream>>>(P, s, W1, b1, W2, b2, out);
}